// Round 1
// baseline (229.072 us; speedup 1.0000x reference)
//
#include <hip/hip_runtime.h>

#define BSZ 2
#define SEQ 2048
#define NH 16
#define DHD 64
#define HDIM 1024   // NH*DHD
#define FS 1024     // input feature size
#define MR (BSZ*SEQ) // 4096

typedef __bf16 bf16x8 __attribute__((ext_vector_type(8)));
typedef float f32x4 __attribute__((ext_vector_type(4)));
typedef unsigned short u16;
typedef unsigned int u32;

__device__ __forceinline__ u16 f2bf(float f) {
  u32 x = __float_as_uint(f);
  return (u16)((x + 0x7fffu + ((x >> 16) & 1u)) >> 16);
}

__device__ __forceinline__ void gload16(const void* g, void* l) {
  __builtin_amdgcn_global_load_lds(
      (const __attribute__((address_space(1))) u32*)g,
      (__attribute__((address_space(3))) u32*)l, 16, 0, 0);
}

// ---------------- cast fp32 -> bf16 (vectorized) ----------------
__global__ __launch_bounds__(256) void cast_k(const float* __restrict__ in,
                                              u16* __restrict__ out, int n4) {
  int i = blockIdx.x * 256 + threadIdx.x;
  const int st = gridDim.x * 256;
  for (; i < n4; i += st) {
    float4 v = ((const float4*)in)[i];
    ushort4 o;
    o.x = f2bf(v.x); o.y = f2bf(v.y); o.z = f2bf(v.z); o.w = f2bf(v.w);
    ((ushort4*)out)[i] = o;
  }
}

// ---------------- W[K][N] fp32 -> WT[N][K] bf16 ----------------
__global__ __launch_bounds__(256) void transw_k(const float* __restrict__ W,
                                                u16* __restrict__ WT) {
  __shared__ float t[32][33];
  const int tx = threadIdx.x, ty = threadIdx.y;
  const int c0 = blockIdx.x * 32, r0 = blockIdx.y * 32;
#pragma unroll
  for (int i = 0; i < 4; i++)
    t[ty + 8 * i][tx] = W[(size_t)(r0 + ty + 8 * i) * FS + c0 + tx];
  __syncthreads();
#pragma unroll
  for (int i = 0; i < 4; i++)
    WT[(size_t)(c0 + ty + 8 * i) * FS + r0 + tx] = f2bf(t[tx][ty + 8 * i]);
}

// ---------------- GEMM: C[M][N] = A[M][K] @ BT[N][K]^T + bias ----------------
// 128x128 tile, BK=64, 4 waves (2x2 of 64x64), global_load_lds staging with
// XOR swizzle (slot ^= row&7) applied on the SOURCE address and on the read.
template <int OUTF32>
__global__ __launch_bounds__(256, 2) void gemm_k(
    const u16* __restrict__ A, const u16* __restrict__ BT,
    const float* __restrict__ bias, void* __restrict__ C,
    int Md, int Nd, int Kd) {
  __shared__ u16 aL[128 * 64];
  __shared__ u16 bL[128 * 64];
  const int nt = Nd >> 7;
  const int m0 = (blockIdx.x / nt) << 7;
  const int n0 = (blockIdx.x % nt) << 7;
  const int tid = threadIdx.x, w = tid >> 6, lane = tid & 63;
  const int wr = ((w >> 1) << 6), wc = ((w & 1) << 6);
  const int li = lane & 15, g = lane >> 4;

  f32x4 acc[4][4];
#pragma unroll
  for (int i = 0; i < 4; i++)
#pragma unroll
    for (int j = 0; j < 4; j++) acc[i][j] = (f32x4){0.f, 0.f, 0.f, 0.f};

  for (int k0 = 0; k0 < Kd; k0 += 64) {
#pragma unroll
    for (int j = 0; j < 4; j++) {
      const int c = w * 4 + j;             // 16 chunks of 8 rows
      const int r = c * 8 + (lane >> 3);
      const int sc = (lane & 7) ^ (r & 7); // pre-swizzled source chunk
      gload16(A + (size_t)(m0 + r) * Kd + k0 + sc * 8, (char*)aL + c * 1024);
      gload16(BT + (size_t)(n0 + r) * Kd + k0 + sc * 8, (char*)bL + c * 1024);
    }
    __syncthreads();
    bf16x8 af[2][4], bfr[2][4];
#pragma unroll
    for (int ks = 0; ks < 2; ks++) {
#pragma unroll
      for (int mf = 0; mf < 4; mf++) {
        const int r = wr + mf * 16 + li;
        const int sl = (g + 4 * ks) ^ (r & 7);
        af[ks][mf] = *(const bf16x8*)((const char*)aL + r * 128 + sl * 16);
      }
#pragma unroll
      for (int nf = 0; nf < 4; nf++) {
        const int r = wc + nf * 16 + li;
        const int sl = (g + 4 * ks) ^ (r & 7);
        bfr[ks][nf] = *(const bf16x8*)((const char*)bL + r * 128 + sl * 16);
      }
    }
#pragma unroll
    for (int ks = 0; ks < 2; ks++)
#pragma unroll
      for (int mf = 0; mf < 4; mf++)
#pragma unroll
        for (int nf = 0; nf < 4; nf++)
          acc[mf][nf] = __builtin_amdgcn_mfma_f32_16x16x32_bf16(
              af[ks][mf], bfr[ks][nf], acc[mf][nf], 0, 0, 0);
    __syncthreads();
  }

#pragma unroll
  for (int mf = 0; mf < 4; mf++)
#pragma unroll
    for (int nf = 0; nf < 4; nf++) {
      const int n = n0 + wc + nf * 16 + li;
      const float bv = bias[n];
#pragma unroll
      for (int r4 = 0; r4 < 4; r4++) {
        const int m = m0 + wr + mf * 16 + g * 4 + r4;
        const float v = acc[mf][nf][r4] + bv;
        if (OUTF32)
          ((float*)C)[(size_t)m * Nd + n] = v;
        else
          ((u16*)C)[(size_t)m * Nd + n] = f2bf(v);
      }
    }
}

// ---------------- flash attention ----------------
// block = (b, h, 64 q rows); 4 waves x 16 q rows; KV tiles of 64.
__global__ __launch_bounds__(256, 3) void attn_k(
    const u16* __restrict__ Qp, const u16* __restrict__ Kp,
    const u16* __restrict__ Vp, u16* __restrict__ Hd) {
  __shared__ u16 qL[64 * 64];    // swizzled rows of 64 bf16
  __shared__ u16 kL[64 * 64];    // swizzled
  __shared__ u16 vT[64 * 72];    // V^T [d][kv], padded stride 72
  __shared__ u16 pL[4 * 16 * 72]; // per-wave P [16][kv], padded stride 72

  const int bid = blockIdx.x;
  const int qb = bid & 31;
  const int h = (bid >> 5) & 15;
  const int b = bid >> 9;
  const int tid = threadIdx.x, w = tid >> 6, lane = tid & 63;
  const int li = lane & 15, g = lane >> 4;
  const int q0 = qb << 6;
  const size_t qbase = (size_t)(b * SEQ + q0) * HDIM + (size_t)h * DHD;
  const size_t kvbase = (size_t)(b * SEQ) * HDIM + (size_t)h * DHD;

  // stage Q tile (swizzled)
#pragma unroll
  for (int j = 0; j < 2; j++) {
    const int c = w * 2 + j;
    const int r = c * 8 + (lane >> 3);
    const int sc = (lane & 7) ^ (r & 7);
    gload16(Qp + qbase + (size_t)r * HDIM + sc * 8, (char*)qL + c * 1024);
  }
  __syncthreads();
  bf16x8 aq[2];
#pragma unroll
  for (int ks = 0; ks < 2; ks++) {
    const int r = w * 16 + li;
    const int sl = (g + 4 * ks) ^ (r & 7);
    aq[ks] = *(const bf16x8*)((const char*)qL + r * 128 + sl * 16);
  }

  float mrun[4], lrun[4];
  f32x4 aco[4];
#pragma unroll
  for (int i = 0; i < 4; i++) {
    mrun[i] = -1e30f; lrun[i] = 0.f;
    aco[i] = (f32x4){0.f, 0.f, 0.f, 0.f};
  }
  u16* pw = pL + w * 16 * 72;

  for (int t = 0; t < SEQ / 64; t++) {
    const size_t kb = kvbase + (size_t)(t * 64) * HDIM;
    // stage K (swizzled, async)
#pragma unroll
    for (int j = 0; j < 2; j++) {
      const int c = w * 2 + j;
      const int r = c * 8 + (lane >> 3);
      const int sc = (lane & 7) ^ (r & 7);
      gload16(Kp + kb + (size_t)r * HDIM + sc * 8, (char*)kL + c * 1024);
    }
    // stage V^T via registers: thread owns 2 d-rows x 8 kv
    {
      const int dd = (tid & 31) * 2;
      const int kvc = tid >> 5;
      u32 pk[8];
#pragma unroll
      for (int k = 0; k < 8; k++)
        pk[k] = *(const u32*)(Vp + kb + (size_t)(kvc * 8 + k) * HDIM + dd);
      uint4 lo, hi;
      lo.x = (pk[0] & 0xffffu) | (pk[1] << 16);
      lo.y = (pk[2] & 0xffffu) | (pk[3] << 16);
      lo.z = (pk[4] & 0xffffu) | (pk[5] << 16);
      lo.w = (pk[6] & 0xffffu) | (pk[7] << 16);
      hi.x = (pk[0] >> 16) | (pk[1] & 0xffff0000u);
      hi.y = (pk[2] >> 16) | (pk[3] & 0xffff0000u);
      hi.z = (pk[4] >> 16) | (pk[5] & 0xffff0000u);
      hi.w = (pk[6] >> 16) | (pk[7] & 0xffff0000u);
      *(uint4*)&vT[(size_t)dd * 72 + kvc * 8] = lo;
      *(uint4*)&vT[(size_t)(dd + 1) * 72 + kvc * 8] = hi;
    }
    __syncthreads();

    // S = Q K^T
    f32x4 s[4];
#pragma unroll
    for (int nf = 0; nf < 4; nf++) s[nf] = (f32x4){0.f, 0.f, 0.f, 0.f};
#pragma unroll
    for (int ks = 0; ks < 2; ks++)
#pragma unroll
      for (int nf = 0; nf < 4; nf++) {
        const int r = nf * 16 + li;
        const int sl = (g + 4 * ks) ^ (r & 7);
        const bf16x8 bk = *(const bf16x8*)((const char*)kL + r * 128 + sl * 16);
        s[nf] = __builtin_amdgcn_mfma_f32_16x16x32_bf16(aq[ks], bk, s[nf], 0, 0, 0);
      }
    // scale 1/sqrt(D)
#pragma unroll
    for (int nf = 0; nf < 4; nf++)
#pragma unroll
      for (int r4 = 0; r4 < 4; r4++) s[nf][r4] *= 0.125f;

    // online softmax (rows: reg r4 within 16-lane group g)
    float p[4][4], scl[4];
#pragma unroll
    for (int r4 = 0; r4 < 4; r4++) {
      float m = fmaxf(fmaxf(s[0][r4], s[1][r4]), fmaxf(s[2][r4], s[3][r4]));
      m = fmaxf(m, __shfl_xor(m, 1));
      m = fmaxf(m, __shfl_xor(m, 2));
      m = fmaxf(m, __shfl_xor(m, 4));
      m = fmaxf(m, __shfl_xor(m, 8));
      const float mnew = fmaxf(mrun[r4], m);
      scl[r4] = __expf(mrun[r4] - mnew);
      mrun[r4] = mnew;
    }
#pragma unroll
    for (int nf = 0; nf < 4; nf++)
#pragma unroll
      for (int r4 = 0; r4 < 4; r4++)
        p[nf][r4] = __expf(s[nf][r4] - mrun[r4]);
#pragma unroll
    for (int r4 = 0; r4 < 4; r4++) {
      float rs = p[0][r4] + p[1][r4] + p[2][r4] + p[3][r4];
      rs += __shfl_xor(rs, 1);
      rs += __shfl_xor(rs, 2);
      rs += __shfl_xor(rs, 4);
      rs += __shfl_xor(rs, 8);
      lrun[r4] = lrun[r4] * scl[r4] + rs;
    }
#pragma unroll
    for (int nf = 0; nf < 4; nf++)
#pragma unroll
      for (int r4 = 0; r4 < 4; r4++) aco[nf][r4] *= scl[r4];

    // P -> LDS (bf16)
#pragma unroll
    for (int nf = 0; nf < 4; nf++)
#pragma unroll
      for (int r4 = 0; r4 < 4; r4++)
        pw[(g * 4 + r4) * 72 + nf * 16 + li] = f2bf(p[nf][r4]);

    // O += P @ V
#pragma unroll
    for (int ks = 0; ks < 2; ks++) {
      const bf16x8 pa = *(const bf16x8*)((const char*)pw + li * 144 + g * 16 + ks * 64);
#pragma unroll
      for (int nf = 0; nf < 4; nf++) {
        const int d = nf * 16 + li;
        const bf16x8 bv = *(const bf16x8*)((const char*)vT + d * 144 + g * 16 + ks * 64);
        aco[nf] = __builtin_amdgcn_mfma_f32_16x16x32_bf16(pa, bv, aco[nf], 0, 0, 0);
      }
    }
    __syncthreads();
  }

  // normalize + write heads (bf16, [b][q][h*64+d] layout)
#pragma unroll
  for (int r4 = 0; r4 < 4; r4++) {
    const float inv = 1.f / lrun[r4];
    const int q = q0 + w * 16 + g * 4 + r4;
    u16* orow = Hd + (size_t)(b * SEQ + q) * HDIM + (size_t)h * DHD;
#pragma unroll
    for (int nf = 0; nf < 4; nf++)
      orow[nf * 16 + li] = f2bf(aco[nf][r4] * inv);
  }
}

// ---------------- launch ----------------
extern "C" void kernel_launch(void* const* d_in, const int* in_sizes, int n_in,
                              void* d_out, int out_size, void* d_ws, size_t ws_size,
                              hipStream_t stream) {
  (void)in_sizes; (void)n_in; (void)out_size; (void)ws_size;
  const float* q_in = (const float*)d_in[0];
  const float* k_in = (const float*)d_in[1];
  const float* v_in = (const float*)d_in[2];
  const float* Wq_w = (const float*)d_in[3];
  const float* Wq_b = (const float*)d_in[4];
  const float* Wk_w = (const float*)d_in[5];
  const float* Wk_b = (const float*)d_in[6];
  const float* Wv_w = (const float*)d_in[7];
  const float* Wv_b = (const float*)d_in[8];
  const float* Wo_w = (const float*)d_in[9];
  const float* Wo_b = (const float*)d_in[10];

  char* ws = (char*)d_ws;
  size_t off = 0;
  auto alloc = [&](size_t n) {
    char* p = ws + off;
    off += (n + 255) & ~(size_t)255;
    return p;
  };
  u16* qb_ = (u16*)alloc((size_t)MR * FS * 2);
  u16* kb_ = (u16*)alloc((size_t)MR * FS * 2);
  u16* vb_ = (u16*)alloc((size_t)MR * FS * 2);
  u16* wqT = (u16*)alloc((size_t)FS * HDIM * 2);
  u16* wkT = (u16*)alloc((size_t)FS * HDIM * 2);
  u16* wvT = (u16*)alloc((size_t)FS * HDIM * 2);
  u16* woT = (u16*)alloc((size_t)HDIM * HDIM * 2);
  u16* Qp = (u16*)alloc((size_t)MR * HDIM * 2);
  u16* Kp = (u16*)alloc((size_t)MR * HDIM * 2);
  u16* Vp = (u16*)alloc((size_t)MR * HDIM * 2);
  u16* Hdp = (u16*)alloc((size_t)MR * HDIM * 2);

  const int n4 = MR * FS / 4;
  cast_k<<<2048, 256, 0, stream>>>(q_in, qb_, n4);
  cast_k<<<2048, 256, 0, stream>>>(k_in, kb_, n4);
  cast_k<<<2048, 256, 0, stream>>>(v_in, vb_, n4);

  dim3 tb(32, 8), tg(FS / 32, FS / 32);
  transw_k<<<tg, tb, 0, stream>>>(Wq_w, wqT);
  transw_k<<<tg, tb, 0, stream>>>(Wk_w, wkT);
  transw_k<<<tg, tb, 0, stream>>>(Wv_w, wvT);
  transw_k<<<tg, tb, 0, stream>>>(Wo_w, woT);

  const int gblocks = (MR / 128) * (HDIM / 128);
  gemm_k<0><<<gblocks, 256, 0, stream>>>(qb_, wqT, Wq_b, Qp, MR, HDIM, FS);
  gemm_k<0><<<gblocks, 256, 0, stream>>>(kb_, wkT, Wk_b, Kp, MR, HDIM, FS);
  gemm_k<0><<<gblocks, 256, 0, stream>>>(vb_, wvT, Wv_b, Vp, MR, HDIM, FS);

  attn_k<<<BSZ * NH * (SEQ / 64), 256, 0, stream>>>(Qp, Kp, Vp, Hdp);

  gemm_k<1><<<gblocks, 256, 0, stream>>>(Hdp, woT, Wo_b, d_out, MR, HDIM, HDIM);
}

// Round 2
// 181.724 us; speedup vs baseline: 1.2605x; 1.2605x over previous
//
#include <hip/hip_runtime.h>

#define BSZ 2
#define SEQ 2048
#define NH 16
#define DHD 64
#define HDIM 1024   // NH*DHD
#define FS 1024     // input feature size
#define MR (BSZ*SEQ) // 4096

typedef __bf16 bf16x8 __attribute__((ext_vector_type(8)));
typedef __bf16 bf16x2t __attribute__((ext_vector_type(2)));
typedef float f32x4 __attribute__((ext_vector_type(4)));
typedef unsigned short u16;
typedef unsigned int u32;

__device__ __forceinline__ u16 f2bf(float f) {
  u32 x = __float_as_uint(f);
  return (u16)((x + 0x7fffu + ((x >> 16) & 1u)) >> 16);
}

__device__ __forceinline__ u32 pack2bf(float a, float b) {
  bf16x2t t = {(__bf16)a, (__bf16)b};
  return __builtin_bit_cast(u32, t);
}

__device__ __forceinline__ void gload16(const void* g, void* l) {
  __builtin_amdgcn_global_load_lds(
      (const __attribute__((address_space(1))) u32*)g,
      (__attribute__((address_space(3))) u32*)l, 16, 0, 0);
}

// ---------------- cast fp32 -> bf16 (vectorized) ----------------
__global__ __launch_bounds__(256) void cast_k(const float* __restrict__ in,
                                              u16* __restrict__ out, int n4) {
  int i = blockIdx.x * 256 + threadIdx.x;
  const int st = gridDim.x * 256;
  for (; i < n4; i += st) {
    float4 v = ((const float4*)in)[i];
    ushort4 o;
    o.x = f2bf(v.x); o.y = f2bf(v.y); o.z = f2bf(v.z); o.w = f2bf(v.w);
    ((ushort4*)out)[i] = o;
  }
}

// ---------------- W[K][N] fp32 -> WT[N][K] bf16 ----------------
__global__ __launch_bounds__(256) void transw_k(const float* __restrict__ W,
                                                u16* __restrict__ WT) {
  __shared__ float t[32][33];
  const int tx = threadIdx.x, ty = threadIdx.y;
  const int c0 = blockIdx.x * 32, r0 = blockIdx.y * 32;
#pragma unroll
  for (int i = 0; i < 4; i++)
    t[ty + 8 * i][tx] = W[(size_t)(r0 + ty + 8 * i) * FS + c0 + tx];
  __syncthreads();
#pragma unroll
  for (int i = 0; i < 4; i++)
    WT[(size_t)(c0 + ty + 8 * i) * FS + r0 + tx] = f2bf(t[tx][ty + 8 * i]);
}

// ---------------- Vp[b][kv][h*64+d] bf16 -> VpT[(b*NH+h)*64+d][kv] bf16 ----
__global__ __launch_bounds__(256) void vtrans_k(const u16* __restrict__ Vp,
                                                u16* __restrict__ VpT) {
  __shared__ u16 tT[64 * 72];  // [d][kv], padded stride 72
  const int bid = blockIdx.x;
  const int kt = bid & 31;
  const int bh = bid >> 5;  // b*NH + h
  const int tid = threadIdx.x;
  const size_t src = (size_t)((bh >> 4) * SEQ + kt * 64) * HDIM + (size_t)(bh & 15) * DHD;
  {
    const int dd = (tid & 31) * 2;
    const int kvc = tid >> 5;
    u32 pk[8];
#pragma unroll
    for (int k = 0; k < 8; k++)
      pk[k] = *(const u32*)(Vp + src + (size_t)(kvc * 8 + k) * HDIM + dd);
    uint4 lo, hi;
    lo.x = (pk[0] & 0xffffu) | (pk[1] << 16);
    lo.y = (pk[2] & 0xffffu) | (pk[3] << 16);
    lo.z = (pk[4] & 0xffffu) | (pk[5] << 16);
    lo.w = (pk[6] & 0xffffu) | (pk[7] << 16);
    hi.x = (pk[0] >> 16) | (pk[1] & 0xffff0000u);
    hi.y = (pk[2] >> 16) | (pk[3] & 0xffff0000u);
    hi.z = (pk[4] >> 16) | (pk[5] & 0xffff0000u);
    hi.w = (pk[6] >> 16) | (pk[7] & 0xffff0000u);
    *(uint4*)&tT[(size_t)dd * 72 + kvc * 8] = lo;
    *(uint4*)&tT[(size_t)(dd + 1) * 72 + kvc * 8] = hi;
  }
  __syncthreads();
  const size_t dst = (size_t)bh * DHD * SEQ + (size_t)kt * 64;
#pragma unroll
  for (int i = 0; i < 2; i++) {
    const int r = (tid >> 3) + 32 * i;
    const int c = (tid & 7) * 8;
    *(uint4*)(VpT + dst + (size_t)r * SEQ + c) = *(const uint4*)&tT[r * 72 + c];
  }
}

// ---------------- GEMM: C[M][N] = (A[M][K] @ BT[N][K]^T + bias) * oscale ----
template <int OUTF32>
__global__ __launch_bounds__(256, 2) void gemm_k(
    const u16* __restrict__ A, const u16* __restrict__ BT,
    const float* __restrict__ bias, void* __restrict__ C,
    int Md, int Nd, int Kd, float oscale) {
  __shared__ u16 aL[128 * 64];
  __shared__ u16 bL[128 * 64];
  const int nt = Nd >> 7;
  const int m0 = (blockIdx.x / nt) << 7;
  const int n0 = (blockIdx.x % nt) << 7;
  const int tid = threadIdx.x, w = tid >> 6, lane = tid & 63;
  const int wr = ((w >> 1) << 6), wc = ((w & 1) << 6);
  const int li = lane & 15, g = lane >> 4;

  f32x4 acc[4][4];
#pragma unroll
  for (int i = 0; i < 4; i++)
#pragma unroll
    for (int j = 0; j < 4; j++) acc[i][j] = (f32x4){0.f, 0.f, 0.f, 0.f};

  for (int k0 = 0; k0 < Kd; k0 += 64) {
#pragma unroll
    for (int j = 0; j < 4; j++) {
      const int c = w * 4 + j;
      const int r = c * 8 + (lane >> 3);
      const int sc = (lane & 7) ^ (r & 7);
      gload16(A + (size_t)(m0 + r) * Kd + k0 + sc * 8, (char*)aL + c * 1024);
      gload16(BT + (size_t)(n0 + r) * Kd + k0 + sc * 8, (char*)bL + c * 1024);
    }
    __syncthreads();
    bf16x8 af[2][4], bfr[2][4];
#pragma unroll
    for (int ks = 0; ks < 2; ks++) {
#pragma unroll
      for (int mf = 0; mf < 4; mf++) {
        const int r = wr + mf * 16 + li;
        const int sl = (g + 4 * ks) ^ (r & 7);
        af[ks][mf] = *(const bf16x8*)((const char*)aL + r * 128 + sl * 16);
      }
#pragma unroll
      for (int nf = 0; nf < 4; nf++) {
        const int r = wc + nf * 16 + li;
        const int sl = (g + 4 * ks) ^ (r & 7);
        bfr[ks][nf] = *(const bf16x8*)((const char*)bL + r * 128 + sl * 16);
      }
    }
#pragma unroll
    for (int ks = 0; ks < 2; ks++)
#pragma unroll
      for (int mf = 0; mf < 4; mf++)
#pragma unroll
        for (int nf = 0; nf < 4; nf++)
          acc[mf][nf] = __builtin_amdgcn_mfma_f32_16x16x32_bf16(
              af[ks][mf], bfr[ks][nf], acc[mf][nf], 0, 0, 0);
    __syncthreads();
  }

#pragma unroll
  for (int mf = 0; mf < 4; mf++)
#pragma unroll
    for (int nf = 0; nf < 4; nf++) {
      const int n = n0 + wc + nf * 16 + li;
      const float bv = bias[n];
#pragma unroll
      for (int r4 = 0; r4 < 4; r4++) {
        const int m = m0 + wr + mf * 16 + g * 4 + r4;
        const float v = (acc[mf][nf][r4] + bv) * oscale;
        if (OUTF32)
          ((float*)C)[(size_t)m * Nd + n] = v;
        else
          ((u16*)C)[(size_t)m * Nd + n] = f2bf(v);
      }
    }
}

// ---------------- flash attention, swapped-QK^T, in-register softmax -------
// block = (b, h, 64 q rows); 4 waves x 16 q rows; KV tiles of 64, dbuf LDS.
__global__ __launch_bounds__(256, 4) void attn_k(
    const u16* __restrict__ Qp, const u16* __restrict__ Kp,
    const u16* __restrict__ VpT, u16* __restrict__ Hd) {
  __shared__ u16 kbuf[2][64 * 64];
  __shared__ u16 vbuf[2][64 * 64];
  __shared__ u16 pbuf[4][16 * 64];  // per-wave P [q=16][kv=64], XOR-swizzled

  const int bid = blockIdx.x;
  const int qb = bid & 31;
  const int h = (bid >> 5) & 15;
  const int b = bid >> 9;
  const int tid = threadIdx.x, w = tid >> 6, lane = tid & 63;
  const int li = lane & 15, g = lane >> 4;
  const int q0 = qb << 6;
  const size_t qbase = (size_t)(b * SEQ + q0) * HDIM + (size_t)h * DHD;
  const size_t kbase = (size_t)(b * SEQ) * HDIM + (size_t)h * DHD;
  const size_t vtbase = (size_t)(b * NH + h) * DHD * SEQ;

  const int c0 = w * 2;          // this thread's two staging chunks
  const int rr = lane >> 3;      // row within chunk
  const int sc8 = ((lane & 7) ^ ((lane >> 3) & 7)) * 8;  // pre-swizzled src elem
  // note: r = c*8 + rr -> r&7 == rr (c*8 has no low bits) for chunk staging

  // ---- stage Q into kbuf[0], read B-fragments ----
#pragma unroll
  for (int j = 0; j < 2; j++) {
    const int c = c0 + j;
    const int r = c * 8 + rr;
    gload16(Qp + qbase + (size_t)r * HDIM + sc8, (char*)kbuf[0] + c * 1024);
  }
  __syncthreads();
  bf16x8 qf[2];
#pragma unroll
  for (int ks = 0; ks < 2; ks++) {
    const int r = w * 16 + li;
    const int sl = (g + 4 * ks) ^ (r & 7);
    qf[ks] = *(const bf16x8*)((const char*)kbuf[0] + r * 128 + sl * 16);
  }
  __syncthreads();

  float mrun = -1e30f, lrun = 0.f;
  f32x4 aco[4];
#pragma unroll
  for (int i = 0; i < 4; i++) aco[i] = (f32x4){0.f, 0.f, 0.f, 0.f};

  char* pw = (char*)pbuf[w] + li * 128;  // this lane's P row base (bytes)
  const int psw = (li & 7) << 4;         // P XOR swizzle

  auto stageKV = [&](int t, int buf) {
    const size_t kb = kbase + (size_t)(t * 64) * HDIM;
    const size_t vb = vtbase + (size_t)(t * 64);
#pragma unroll
    for (int j = 0; j < 2; j++) {
      const int c = c0 + j;
      const int r = c * 8 + rr;
      gload16(Kp + kb + (size_t)r * HDIM + sc8, (char*)kbuf[buf] + c * 1024);
      gload16(VpT + vb + (size_t)r * SEQ + sc8, (char*)vbuf[buf] + c * 1024);
    }
  };

  stageKV(0, 0);

  for (int t = 0; t < SEQ / 64; t++) {
    __syncthreads();  // drains stage(t) vmcnt + lgkm (compiler-emitted)
    const int cur = t & 1;
    if (t + 1 < SEQ / 64) stageKV(t + 1, cur ^ 1);  // in flight across compute

    // ---- S^T = K @ Q^T : lane holds S[q=li][kv = 16c+4g+reg] ----
    const char* kl = (const char*)kbuf[cur];
    f32x4 s[4];
#pragma unroll
    for (int c = 0; c < 4; c++) s[c] = (f32x4){0.f, 0.f, 0.f, 0.f};
#pragma unroll
    for (int ks = 0; ks < 2; ks++)
#pragma unroll
      for (int c = 0; c < 4; c++) {
        const int r = c * 16 + li;
        const int sl = (g + 4 * ks) ^ (r & 7);
        const bf16x8 kf = *(const bf16x8*)(kl + r * 128 + sl * 16);
        s[c] = __builtin_amdgcn_mfma_f32_16x16x32_bf16(kf, qf[ks], s[c], 0, 0, 0);
      }

    // ---- online softmax, fully in-register (q = li per lane) ----
    float mx = s[0][0];
#pragma unroll
    for (int c = 0; c < 4; c++)
#pragma unroll
      for (int r4 = 0; r4 < 4; r4++) mx = fmaxf(mx, s[c][r4]);
    mx = fmaxf(mx, __shfl_xor(mx, 16));
    mx = fmaxf(mx, __shfl_xor(mx, 32));
    const float mnew = fmaxf(mrun, mx);
    const float scl = __expf(mrun - mnew);
    mrun = mnew;
    float p[4][4];
    float rs = 0.f;
#pragma unroll
    for (int c = 0; c < 4; c++)
#pragma unroll
      for (int r4 = 0; r4 < 4; r4++) {
        p[c][r4] = __expf(s[c][r4] - mnew);
        rs += p[c][r4];
      }
    rs += __shfl_xor(rs, 16);
    rs += __shfl_xor(rs, 32);
    lrun = lrun * scl + rs;
#pragma unroll
    for (int nf = 0; nf < 4; nf++)
#pragma unroll
      for (int r4 = 0; r4 < 4; r4++) aco[nf][r4] *= scl;

    // ---- P -> per-wave LDS (swizzled b64 writes), in-wave exchange ----
#pragma unroll
    for (int c = 0; c < 4; c++) {
      uint2 d2;
      d2.x = pack2bf(p[c][0], p[c][1]);
      d2.y = pack2bf(p[c][2], p[c][3]);
      *(uint2*)(pw + ((32 * c + 8 * g) ^ psw)) = d2;
    }

    // ---- O^T += V^T @ P^T : aco[nf][reg] = O[q=li][d=16nf+4g+reg] ----
    const char* vl = (const char*)vbuf[cur];
#pragma unroll
    for (int ks = 0; ks < 2; ks++) {
      const bf16x8 pf = *(const bf16x8*)(pw + ((64 * ks + 16 * g) ^ psw));
#pragma unroll
      for (int nf = 0; nf < 4; nf++) {
        const int r = nf * 16 + li;
        const int sl = (g + 4 * ks) ^ (r & 7);
        const bf16x8 vf = *(const bf16x8*)(vl + r * 128 + sl * 16);
        aco[nf] = __builtin_amdgcn_mfma_f32_16x16x32_bf16(vf, pf, aco[nf], 0, 0, 0);
      }
    }
  }

  // ---- normalize + write heads: lane owns q = q0+w*16+li ----
  const float inv = 1.f / lrun;
  const int q = q0 + w * 16 + li;
  u16* orow = Hd + (size_t)(b * SEQ + q) * HDIM + (size_t)h * DHD;
#pragma unroll
  for (int nf = 0; nf < 4; nf++) {
    ushort4 o;
    o.x = f2bf(aco[nf][0] * inv);
    o.y = f2bf(aco[nf][1] * inv);
    o.z = f2bf(aco[nf][2] * inv);
    o.w = f2bf(aco[nf][3] * inv);
    *(ushort4*)(orow + nf * 16 + g * 4) = o;
  }
}

// ---------------- launch ----------------
extern "C" void kernel_launch(void* const* d_in, const int* in_sizes, int n_in,
                              void* d_out, int out_size, void* d_ws, size_t ws_size,
                              hipStream_t stream) {
  (void)in_sizes; (void)n_in; (void)out_size; (void)ws_size;
  const float* q_in = (const float*)d_in[0];
  const float* k_in = (const float*)d_in[1];
  const float* v_in = (const float*)d_in[2];
  const float* Wq_w = (const float*)d_in[3];
  const float* Wq_b = (const float*)d_in[4];
  const float* Wk_w = (const float*)d_in[5];
  const float* Wk_b = (const float*)d_in[6];
  const float* Wv_w = (const float*)d_in[7];
  const float* Wv_b = (const float*)d_in[8];
  const float* Wo_w = (const float*)d_in[9];
  const float* Wo_b = (const float*)d_in[10];

  char* ws = (char*)d_ws;
  size_t off = 0;
  auto alloc = [&](size_t n) {
    char* p = ws + off;
    off += (n + 255) & ~(size_t)255;
    return p;
  };
  u16* qb_ = (u16*)alloc((size_t)MR * FS * 2);
  u16* kb_ = (u16*)alloc((size_t)MR * FS * 2);
  u16* vb_ = (u16*)alloc((size_t)MR * FS * 2);
  u16* wqT = (u16*)alloc((size_t)FS * HDIM * 2);
  u16* wkT = (u16*)alloc((size_t)FS * HDIM * 2);
  u16* wvT = (u16*)alloc((size_t)FS * HDIM * 2);
  u16* woT = (u16*)alloc((size_t)HDIM * HDIM * 2);
  u16* Qp = (u16*)alloc((size_t)MR * HDIM * 2);
  u16* Kp = (u16*)alloc((size_t)MR * HDIM * 2);
  u16* Vp = (u16*)alloc((size_t)MR * HDIM * 2);
  u16* Hdp = (u16*)alloc((size_t)MR * HDIM * 2);
  u16* VpT = qb_;  // reuse: qb_ dead after Q projection GEMM

  const int n4 = MR * FS / 4;
  cast_k<<<2048, 256, 0, stream>>>(q_in, qb_, n4);
  cast_k<<<2048, 256, 0, stream>>>(k_in, kb_, n4);
  cast_k<<<2048, 256, 0, stream>>>(v_in, vb_, n4);

  dim3 tb(32, 8), tg(FS / 32, FS / 32);
  transw_k<<<tg, tb, 0, stream>>>(Wq_w, wqT);
  transw_k<<<tg, tb, 0, stream>>>(Wk_w, wkT);
  transw_k<<<tg, tb, 0, stream>>>(Wv_w, wvT);
  transw_k<<<tg, tb, 0, stream>>>(Wo_w, woT);

  const int gblocks = (MR / 128) * (HDIM / 128);
  gemm_k<0><<<gblocks, 256, 0, stream>>>(qb_, wqT, Wq_b, Qp, MR, HDIM, FS, 0.125f);
  gemm_k<0><<<gblocks, 256, 0, stream>>>(kb_, wkT, Wk_b, Kp, MR, HDIM, FS, 1.0f);
  gemm_k<0><<<gblocks, 256, 0, stream>>>(vb_, wvT, Wv_b, Vp, MR, HDIM, FS, 1.0f);

  vtrans_k<<<BSZ * NH * (SEQ / 64), 256, 0, stream>>>(Vp, VpT);

  attn_k<<<BSZ * NH * (SEQ / 64), 256, 0, stream>>>(Qp, Kp, VpT, Hdp);

  gemm_k<1><<<gblocks, 256, 0, stream>>>(Hdp, woT, Wo_b, d_out, MR, HDIM, HDIM, 1.0f);
}